// Round 3
// baseline (238.904 us; speedup 1.0000x reference)
//
#include <hip/hip_runtime.h>
#include <hip/hip_bf16.h>

// GRU fused kernel for MI355X (gfx950). R8: depth-3 software pipeline on the
// x-stream. R7 evidence: per-step wall (~7900 cyc) == system drain time of the
// step's 8.4MB x-slab at the latency-limited 2.3 TB/s equilibrium; per-wave
// MLP was 4 loads issued/waited per step (prefetch depth 1). R8 triple-buffers
// x in registers (sets A/B/C, static rotation via unroll-by-3), so loads are
// issued 3 steps ahead and the vmcnt wait covers loads issued 2 steps ago.
// Keeps R7's shuffle-free recurrence: W_hh cols (and Wout rows) tau-permuted
// at staging so pack8(h0a,h0b) IS the next B-fragment (zero cross-lane ops);
// hoisted weight fragments in VGPRs; exp2-folded gates; dual pixel-group.
// T=24, N=65536 pixels, F=H=32, gates r,z,n (3H=96); one wave = 32 px.

#define TSTEPS 24
#define NPIX 65536
#define PADW 40   // shorts per weight row in LDS (80 B) — breaks bank aliasing

typedef __attribute__((ext_vector_type(8))) short bf16x8;
typedef __attribute__((ext_vector_type(4))) float f32x4;
typedef __attribute__((ext_vector_type(4))) unsigned int u32x4;

#define MFMA16(a, b, c) __builtin_amdgcn_mfma_f32_16x16x32_bf16((a), (b), (c), 0, 0, 0)

#define SCL_RZ (-1.4426950408889634f)   // -log2(e): sigmoid(x) = rcp(1+exp2(-x*log2e))
#define SCL_N  ( 2.8853900817779268f)   // 2*log2(e): tanh(y) = 1-2*rcp(1+exp2(2y*log2e))

__device__ __forceinline__ unsigned short f2bf(float f) {
  unsigned u = __builtin_bit_cast(unsigned, f);
  u += 0x7fffu + ((u >> 16) & 1u);   // RNE (one-time staging only)
  return (unsigned short)(u >> 16);
}

// pack two f32 -> dword (bf16(a) low | bf16(b) high) via HW v_cvt_pk_bf16_f32
__device__ __forceinline__ unsigned pk2(float a, float b) {
  __hip_bfloat162 h = __float22bfloat162_rn(float2{a, b});
  unsigned u;
  __builtin_memcpy(&u, &h, sizeof(u));
  return u;
}

__device__ __forceinline__ bf16x8 pack8(f32x4 a, f32x4 b) {
  u32x4 r = { pk2(a[0], a[1]), pk2(a[2], a[3]), pk2(b[0], b[1]), pk2(b[2], b[3]) };
  return __builtin_bit_cast(bf16x8, r);
}

// sigmoid(x) given t = -x*log2e (scale folded into weights upstream)
__device__ __forceinline__ float sig2(float t) {
  return __builtin_amdgcn_rcpf(1.f + __builtin_amdgcn_exp2f(t));
}
// tanh(y) given t = 2y*log2e (scale folded into weights upstream)
__device__ __forceinline__ float tanh2(float t) {
  return 1.f - 2.f * __builtin_amdgcn_rcpf(1.f + __builtin_amdgcn_exp2f(t));
}

// tau: B-fragment k-slot -> state position (C-layout row), per 8-slot quad
__device__ __forceinline__ int tau(int k) {
  int q = k >> 3, j = k & 7;
  return (j < 4) ? (q * 4 + j) : (16 + q * 4 + (j - 4));
}

__global__ __launch_bounds__(256, 2)
void gru_fused(const float* __restrict__ spatial, const float* __restrict__ met,
               const float* __restrict__ ctx,
               const float* __restrict__ W_ih, const float* __restrict__ W_hh,
               const float* __restrict__ b_ih, const float* __restrict__ b_hh,
               const float* __restrict__ Wout, float* __restrict__ out) {
  // rows 0..95 = W_ih (scaled), rows 96..191 = W_hh (scaled, tau-permuted cols)
  __shared__ __align__(16) unsigned short sW[192 * PADW];
  __shared__ __align__(16) float sCB[64];   // (b_ih+b_hh)*SCL_RZ rows 0..63 (r,z)
  __shared__ __align__(16) float sBIN[32];  // b_ih*SCL_N rows 64..95 (n)
  __shared__ __align__(16) float sBHN[32];  // b_hh*SCL_N rows 64..95 (n)

  const int tid = threadIdx.x;
  for (int i = tid; i < 96 * 32; i += 256) {
    int r = i >> 5, c = i & 31;
    float s = (r < 64) ? SCL_RZ : SCL_N;
    sW[r * PADW + c] = f2bf(W_ih[i] * s);
    sW[(96 + r) * PADW + c] = f2bf(W_hh[r * 32 + tau(c)] * s);
  }
  if (tid < 64) sCB[tid] = (b_ih[tid] + b_hh[tid]) * SCL_RZ;
  else if (tid < 96) sBIN[tid - 64] = b_ih[tid] * SCL_N;
  else if (tid < 128) sBHN[tid - 96] = b_hh[tid - 32] * SCL_N;
  __syncthreads();

  const int lane = tid & 63;
  const int col = lane & 15;     // pixel column within group (also A-frag row)
  const int q = lane >> 4;       // k-quad
  const int wave = blockIdx.x * 4 + (tid >> 6);
  const long p0 = (long)wave * 32 + col;   // group 0 pixel
  const long p1 = p0 + 16;                 // group 1 pixel

  // biases resident (read once from LDS), pre-scaled
  f32x4 cS[4];
#pragma unroll
  for (int i = 0; i < 4; ++i) cS[i] = *(const f32x4*)&sCB[i * 16 + q * 4];
  const f32x4 cG4 = *(const f32x4*)&sBIN[q * 4];
  const f32x4 cG5 = *(const f32x4*)&sBIN[16 + q * 4];
  const f32x4 cH4 = *(const f32x4*)&sBHN[q * 4];
  const f32x4 cH5 = *(const f32x4*)&sBHN[16 + q * 4];

  // weight fragments hoisted to registers once (loop-invariant)
  const int wb = col * PADW + q * 8;   // fragment base (shorts)
  const bf16x8 a0 = *(const bf16x8*)&sW[wb];
  const bf16x8 a1 = *(const bf16x8*)&sW[wb + 16 * PADW];
  const bf16x8 a2 = *(const bf16x8*)&sW[wb + 32 * PADW];
  const bf16x8 a3 = *(const bf16x8*)&sW[wb + 48 * PADW];
  const bf16x8 a4 = *(const bf16x8*)&sW[wb + 64 * PADW];
  const bf16x8 a5 = *(const bf16x8*)&sW[wb + 80 * PADW];
  const bf16x8 w0 = *(const bf16x8*)&sW[wb + 96 * PADW];
  const bf16x8 w1 = *(const bf16x8*)&sW[wb + 112 * PADW];
  const bf16x8 w2 = *(const bf16x8*)&sW[wb + 128 * PADW];
  const bf16x8 w3 = *(const bf16x8*)&sW[wb + 144 * PADW];
  const bf16x8 w4 = *(const bf16x8*)&sW[wb + 160 * PADW];
  const bf16x8 w5 = *(const bf16x8*)&sW[wb + 176 * PADW];

  // per-lane x streams (lane provides x^T[k=q*8+j][col] for each group)
  const float *xp0, *xp1;
  long xstride;
  if (q < 2) {
    xp0 = spatial + p0 * 16 + q * 8; xp1 = spatial + p1 * 16 + q * 8;
    xstride = (long)NPIX * 16;
  } else if (q == 2) {
    xp0 = met + p0 * 8; xp1 = met + p1 * 8; xstride = (long)NPIX * 8;
  } else {
    xp0 = ctx + p0 * 8; xp1 = ctx + p1 * 8; xstride = (long)NPIX * 8;
  }

  // triple-buffered f32 staging sets (static rotation; no runtime indexing)
  f32x4 A0a, A0b, A1a, A1b;
  f32x4 B0a, B0b, B1a, B1b;
  f32x4 C0a, C0b, C1a, C1b;

#define LOADX(P0a, P0b, P1a, P1b)                                  \
  do {                                                             \
    P0a = *(const f32x4*)xp0; P0b = *(const f32x4*)(xp0 + 4);      \
    P1a = *(const f32x4*)xp1; P1b = *(const f32x4*)(xp1 + 4);      \
    xp0 += xstride; xp1 += xstride;                                \
  } while (0)

  LOADX(C0a, C0b, C1a, C1b);   // x[0]
  LOADX(A0a, A0b, A1a, A1b);   // x[1]
  LOADX(B0a, B0b, B1a, B1b);   // x[2]
  bf16x8 bx0 = pack8(C0a, C0b);
  bf16x8 bx1 = pack8(C1a, C1b);

  f32x4 h0a = {0.f, 0.f, 0.f, 0.f}, h0b = {0.f, 0.f, 0.f, 0.f};   // group 0
  f32x4 h1a = {0.f, 0.f, 0.f, 0.f}, h1b = {0.f, 0.f, 0.f, 0.f};   // group 1
  const f32x4 zero = {0.f, 0.f, 0.f, 0.f};

  // One GRU step. NX* = set holding x[t+1] (packed into bx at end);
  // LD* = free set receiving loads for x[t+3]. The vmcnt wait at the pack
  // covers loads issued two full steps earlier.
#define STEPBODY(NX0a, NX0b, NX1a, NX1b, LD0a, LD0b, LD1a, LD1b, DOLOAD, DOPACK) \
  do {                                                                           \
    if (DOLOAD) { LOADX(LD0a, LD0b, LD1a, LD1b); }                               \
    bf16x8 bh0 = pack8(h0a, h0b);                                                \
    bf16x8 bh1 = pack8(h1a, h1b);                                                \
    f32x4 G00 = MFMA16(a0, bx0, cS[0]);  f32x4 G10 = MFMA16(a0, bx1, cS[0]);     \
    f32x4 G01 = MFMA16(a1, bx0, cS[1]);  f32x4 G11 = MFMA16(a1, bx1, cS[1]);     \
    f32x4 G02 = MFMA16(a2, bx0, cS[2]);  f32x4 G12 = MFMA16(a2, bx1, cS[2]);     \
    f32x4 G03 = MFMA16(a3, bx0, cS[3]);  f32x4 G13 = MFMA16(a3, bx1, cS[3]);     \
    f32x4 G04 = MFMA16(a4, bx0, cG4);    f32x4 G14 = MFMA16(a4, bx1, cG4);       \
    f32x4 G05 = MFMA16(a5, bx0, cG5);    f32x4 G15 = MFMA16(a5, bx1, cG5);       \
    f32x4 R00 = MFMA16(w0, bh0, G00);    f32x4 R10 = MFMA16(w0, bh1, G10);       \
    f32x4 R01 = MFMA16(w1, bh0, G01);    f32x4 R11 = MFMA16(w1, bh1, G11);       \
    f32x4 Z00 = MFMA16(w2, bh0, G02);    f32x4 Z10 = MFMA16(w2, bh1, G12);       \
    f32x4 Z01 = MFMA16(w3, bh0, G03);    f32x4 Z11 = MFMA16(w3, bh1, G13);       \
    f32x4 H04 = MFMA16(w4, bh0, cH4);    f32x4 H14 = MFMA16(w4, bh1, cH4);       \
    f32x4 H05 = MFMA16(w5, bh0, cH5);    f32x4 H15 = MFMA16(w5, bh1, cH5);       \
    _Pragma("unroll")                                                            \
    for (int r = 0; r < 4; ++r) {                                                \
      float r00 = sig2(R00[r]);                                                  \
      float r01 = sig2(R01[r]);                                                  \
      float z00 = sig2(Z00[r]);                                                  \
      float z01 = sig2(Z01[r]);                                                  \
      float n00 = tanh2(__builtin_fmaf(r00, H04[r], G04[r]));                    \
      float n01 = tanh2(__builtin_fmaf(r01, H05[r], G05[r]));                    \
      h0a[r] = n00 + z00 * (h0a[r] - n00);                                       \
      h0b[r] = n01 + z01 * (h0b[r] - n01);                                       \
      float r10 = sig2(R10[r]);                                                  \
      float r11 = sig2(R11[r]);                                                  \
      float z10 = sig2(Z10[r]);                                                  \
      float z11 = sig2(Z11[r]);                                                  \
      float n10 = tanh2(__builtin_fmaf(r10, H14[r], G14[r]));                    \
      float n11 = tanh2(__builtin_fmaf(r11, H15[r], G15[r]));                    \
      h1a[r] = n10 + z10 * (h1a[r] - n10);                                       \
      h1b[r] = n11 + z11 * (h1b[r] - n11);                                       \
    }                                                                            \
    if (DOPACK) {                                                                \
      bx0 = pack8(NX0a, NX0b);                                                   \
      bx1 = pack8(NX1a, NX1b);                                                   \
    }                                                                            \
  } while (0)

  // invariant at top of iteration tt: bx = x[3tt], A = x[3tt+1], B = x[3tt+2]
#pragma unroll 1
  for (int tt = 0; tt < 8; ++tt) {
    const bool ld = (tt < 7);
    // t = 3tt:   load x[3tt+3] -> C, pack A
    STEPBODY(A0a, A0b, A1a, A1b, C0a, C0b, C1a, C1b, ld, true);
    // t = 3tt+1: load x[3tt+4] -> A, pack B
    STEPBODY(B0a, B0b, B1a, B1b, A0a, A0b, A1a, A1b, ld, true);
    // t = 3tt+2: load x[3tt+5] -> B, pack C
    STEPBODY(C0a, C0b, C1a, C1b, B0a, B0b, B1a, B1b, ld, ld);
  }

  // epilogue: out^T(16x16) = W^T(16x32) @ h^T(32x16) per group.
  // B-frag is the same tau-packed state, so Wout rows are read tau-permuted.
  bf16x8 bhf0 = pack8(h0a, h0b);
  bf16x8 bhf1 = pack8(h1a, h1b);
  float w[8];
#pragma unroll
  for (int j = 0; j < 8; ++j) {
    int tk = (j < 4) ? (q * 4 + j) : (16 + q * 4 + (j - 4));   // tau(q*8+j)
    w[j] = Wout[tk * 16 + col];
  }
  u32x4 awp = { pk2(w[0], w[1]), pk2(w[2], w[3]), pk2(w[4], w[5]), pk2(w[6], w[7]) };
  bf16x8 aw = __builtin_bit_cast(bf16x8, awp);
  f32x4 o0 = MFMA16(aw, bhf0, zero);
  f32x4 o1 = MFMA16(aw, bhf1, zero);
  *(f32x4*)&out[p0 * 16 + q * 4] = o0;
  *(f32x4*)&out[p1 * 16 + q * 4] = o1;
}

extern "C" void kernel_launch(void* const* d_in, const int* in_sizes, int n_in,
                              void* d_out, int out_size, void* d_ws, size_t ws_size,
                              hipStream_t stream) {
  const float* spatial = (const float*)d_in[0];
  const float* met     = (const float*)d_in[1];
  const float* ctx     = (const float*)d_in[2];
  const float* W_ih    = (const float*)d_in[3];
  const float* W_hh    = (const float*)d_in[4];
  const float* b_ih    = (const float*)d_in[5];
  const float* b_hh    = (const float*)d_in[6];
  const float* Wout    = (const float*)d_in[7];
  float* out = (float*)d_out;

  // 2048 waves x 32 px; 512 blocks of 256 = 2 blocks/CU, 8 waves/CU
  gru_fused<<<dim3(NPIX / 32 / 4), dim3(256), 0, stream>>>(
      spatial, met, ctx, W_ih, W_hh, b_ih, b_hh, Wout, out);
}

// Round 4
// 237.519 us; speedup vs baseline: 1.0058x; 1.0058x over previous
//
#include <hip/hip_runtime.h>
#include <hip/hip_bf16.h>

// GRU fused kernel for MI355X (gfx950). R9: manually-counted streaming ingest.
// R5-R8 evidence: ~87us invariant across instruction-stream variants; compute
// (VALU 34%, MFMA 8%) and all BW tiers are far from limits => the machine is
// stop-and-go: compiler-controlled vmcnt drains serialize each wave's loads,
// synchronizing the chip into alternating memory/compute phases (effective
// 2.3 TB/s vs 6.3 achievable). Fix: global_load_lds + inline-asm counted
// s_waitcnt vmcnt(N) (the only wait discipline the compiler can't rewrite).
// 3-slab LDS ring, per-wave-private regions (no barriers in loop); loads for
// step t+2 issued at step t; vmcnt(8) keeps 2 steps permanently in flight.
// Keeps R7's shuffle-free recurrence (tau-permuted W_hh/Wout so pack8(h) IS
// the B-fragment), hoisted weight frags in VGPRs, exp2-folded gates,
// dual pixel-group. T=24, N=65536, F=H=32, gates r,z,n; one wave = 32 px.

#define TSTEPS 24
#define NPIX 65536
#define PADW 40        // shorts per weight row in LDS (80 B)
#define RING_STEP 16384  // bytes per ring slab: 4 waves * 4 KB

typedef __attribute__((ext_vector_type(8))) short bf16x8;
typedef __attribute__((ext_vector_type(4))) float f32x4;
typedef __attribute__((ext_vector_type(4))) unsigned int u32x4;

#define MFMA16(a, b, c) __builtin_amdgcn_mfma_f32_16x16x32_bf16((a), (b), (c), 0, 0, 0)

#define SCL_RZ (-1.4426950408889634f)   // -log2(e)
#define SCL_N  ( 2.8853900817779268f)   // 2*log2(e)

__device__ __forceinline__ unsigned short f2bf(float f) {
  unsigned u = __builtin_bit_cast(unsigned, f);
  u += 0x7fffu + ((u >> 16) & 1u);   // RNE (one-time staging only)
  return (unsigned short)(u >> 16);
}

__device__ __forceinline__ unsigned pk2(float a, float b) {
  __hip_bfloat162 h = __float22bfloat162_rn(float2{a, b});
  unsigned u;
  __builtin_memcpy(&u, &h, sizeof(u));
  return u;
}

__device__ __forceinline__ bf16x8 pack8(f32x4 a, f32x4 b) {
  u32x4 r = { pk2(a[0], a[1]), pk2(a[2], a[3]), pk2(b[0], b[1]), pk2(b[2], b[3]) };
  return __builtin_bit_cast(bf16x8, r);
}

__device__ __forceinline__ float sig2(float t) {
  return __builtin_amdgcn_rcpf(1.f + __builtin_amdgcn_exp2f(t));
}
__device__ __forceinline__ float tanh2(float t) {
  return 1.f - 2.f * __builtin_amdgcn_rcpf(1.f + __builtin_amdgcn_exp2f(t));
}

// tau: B-fragment k-slot -> state position (C-layout row), per 8-slot quad
__device__ __forceinline__ int tau(int k) {
  int q = k >> 3, j = k & 7;
  return (j < 4) ? (q * 4 + j) : (16 + q * 4 + (j - 4));
}

#define AS1 __attribute__((address_space(1)))
#define AS3 __attribute__((address_space(3)))

__global__ __launch_bounds__(256, 2)
void gru_fused(const float* __restrict__ spatial, const float* __restrict__ met,
               const float* __restrict__ ctx,
               const float* __restrict__ W_ih, const float* __restrict__ W_hh,
               const float* __restrict__ b_ih, const float* __restrict__ b_hh,
               const float* __restrict__ Wout, float* __restrict__ out) {
  // x-ingest ring: 3 slabs x (4 waves x 4 KB). Wave-private regions.
  __shared__ __align__(16) unsigned char ring[3 * RING_STEP];
  // rows 0..95 = W_ih (scaled), rows 96..191 = W_hh (scaled, tau-permuted cols)
  __shared__ __align__(16) unsigned short sW[192 * PADW];
  __shared__ __align__(16) float sCB[64];
  __shared__ __align__(16) float sBIN[32];
  __shared__ __align__(16) float sBHN[32];

  const int tid = threadIdx.x;
  for (int i = tid; i < 96 * 32; i += 256) {
    int r = i >> 5, c = i & 31;
    float s = (r < 64) ? SCL_RZ : SCL_N;
    sW[r * PADW + c] = f2bf(W_ih[i] * s);
    sW[(96 + r) * PADW + c] = f2bf(W_hh[r * 32 + tau(c)] * s);
  }
  if (tid < 64) sCB[tid] = (b_ih[tid] + b_hh[tid]) * SCL_RZ;
  else if (tid < 96) sBIN[tid - 64] = b_ih[tid] * SCL_N;
  else if (tid < 128) sBHN[tid - 96] = b_hh[tid - 32] * SCL_N;
  __syncthreads();

  const int lane = tid & 63;
  const int col = lane & 15;
  const int q = lane >> 4;
  const int wv = tid >> 6;                  // wave in block
  const int wave = blockIdx.x * 4 + wv;
  const long p0 = (long)wave * 32 + col;    // group 0 pixel
  const long p1 = p0 + 16;                  // group 1 pixel

  // biases resident (read once from LDS), pre-scaled
  f32x4 cS[4];
#pragma unroll
  for (int i = 0; i < 4; ++i) cS[i] = *(const f32x4*)&sCB[i * 16 + q * 4];
  const f32x4 cG4 = *(const f32x4*)&sBIN[q * 4];
  const f32x4 cG5 = *(const f32x4*)&sBIN[16 + q * 4];
  const f32x4 cH4 = *(const f32x4*)&sBHN[q * 4];
  const f32x4 cH5 = *(const f32x4*)&sBHN[16 + q * 4];

  // weight fragments hoisted to registers once (loop-invariant)
  const int wb = col * PADW + q * 8;
  const bf16x8 a0 = *(const bf16x8*)&sW[wb];
  const bf16x8 a1 = *(const bf16x8*)&sW[wb + 16 * PADW];
  const bf16x8 a2 = *(const bf16x8*)&sW[wb + 32 * PADW];
  const bf16x8 a3 = *(const bf16x8*)&sW[wb + 48 * PADW];
  const bf16x8 a4 = *(const bf16x8*)&sW[wb + 64 * PADW];
  const bf16x8 a5 = *(const bf16x8*)&sW[wb + 80 * PADW];
  const bf16x8 w0 = *(const bf16x8*)&sW[wb + 96 * PADW];
  const bf16x8 w1 = *(const bf16x8*)&sW[wb + 112 * PADW];
  const bf16x8 w2 = *(const bf16x8*)&sW[wb + 128 * PADW];
  const bf16x8 w3 = *(const bf16x8*)&sW[wb + 144 * PADW];
  const bf16x8 w4 = *(const bf16x8*)&sW[wb + 160 * PADW];
  const bf16x8 w5 = *(const bf16x8*)&sW[wb + 176 * PADW];

  // per-lane x streams (lane supplies x^T[k=q*8+j][col] for each group)
  const float *xp0, *xp1;
  long xstride;
  if (q < 2) {
    xp0 = spatial + p0 * 16 + q * 8; xp1 = spatial + p1 * 16 + q * 8;
    xstride = (long)NPIX * 16;
  } else if (q == 2) {
    xp0 = met + p0 * 8; xp1 = met + p1 * 8; xstride = (long)NPIX * 8;
  } else {
    xp0 = ctx + p0 * 8; xp1 = ctx + p1 * 8; xstride = (long)NPIX * 8;
  }

  // all staging vmem has drained (compiler waits before ds_write/syncthreads),
  // so gl_lds below are the ONLY vmcnt events in the loop: counts are exact.
#define ISSUE_X(SLAB)                                                          \
  do {                                                                         \
    unsigned char* lb = &ring[(SLAB) * RING_STEP + wv * 4096];                 \
    __builtin_amdgcn_global_load_lds((const AS1 unsigned int*)xp0,             \
                                     (AS3 unsigned int*)(lb), 16, 0, 0);       \
    __builtin_amdgcn_global_load_lds((const AS1 unsigned int*)(xp0 + 4),       \
                                     (AS3 unsigned int*)(lb + 1024), 16, 0, 0);\
    __builtin_amdgcn_global_load_lds((const AS1 unsigned int*)xp1,             \
                                     (AS3 unsigned int*)(lb + 2048), 16, 0, 0);\
    __builtin_amdgcn_global_load_lds((const AS1 unsigned int*)(xp1 + 4),       \
                                     (AS3 unsigned int*)(lb + 3072), 16, 0, 0);\
    xp0 += xstride; xp1 += xstride;                                            \
  } while (0)

  f32x4 h0a = {0.f, 0.f, 0.f, 0.f}, h0b = {0.f, 0.f, 0.f, 0.f};   // group 0
  f32x4 h1a = {0.f, 0.f, 0.f, 0.f}, h1b = {0.f, 0.f, 0.f, 0.f};   // group 1
  const f32x4 zero = {0.f, 0.f, 0.f, 0.f};

  // One step: issue loads for t+2 into slab WS, counted-wait for slab RS
  // (WAIT = # gl_lds newer than slab RS's 4), consume RS, compute.
#define STEPW(RS, WS, DOLOAD, WAIT)                                            \
  do {                                                                         \
    if (DOLOAD) ISSUE_X(WS);                                                   \
    asm volatile("s_waitcnt " WAIT ::: "memory");                              \
    __builtin_amdgcn_sched_barrier(0);                                         \
    const unsigned char* rb = &ring[(RS) * RING_STEP + wv * 4096 + lane * 16]; \
    f32x4 x0a = *(const f32x4*)(rb);                                           \
    f32x4 x0b = *(const f32x4*)(rb + 1024);                                    \
    f32x4 x1a = *(const f32x4*)(rb + 2048);                                    \
    f32x4 x1b = *(const f32x4*)(rb + 3072);                                    \
    bf16x8 bx0 = pack8(x0a, x0b);                                              \
    bf16x8 bx1 = pack8(x1a, x1b);                                              \
    bf16x8 bh0 = pack8(h0a, h0b);                                              \
    bf16x8 bh1 = pack8(h1a, h1b);                                              \
    f32x4 G00 = MFMA16(a0, bx0, cS[0]);  f32x4 G10 = MFMA16(a0, bx1, cS[0]);   \
    f32x4 G01 = MFMA16(a1, bx0, cS[1]);  f32x4 G11 = MFMA16(a1, bx1, cS[1]);   \
    f32x4 G02 = MFMA16(a2, bx0, cS[2]);  f32x4 G12 = MFMA16(a2, bx1, cS[2]);   \
    f32x4 G03 = MFMA16(a3, bx0, cS[3]);  f32x4 G13 = MFMA16(a3, bx1, cS[3]);   \
    f32x4 G04 = MFMA16(a4, bx0, cG4);    f32x4 G14 = MFMA16(a4, bx1, cG4);     \
    f32x4 G05 = MFMA16(a5, bx0, cG5);    f32x4 G15 = MFMA16(a5, bx1, cG5);     \
    f32x4 R00 = MFMA16(w0, bh0, G00);    f32x4 R10 = MFMA16(w0, bh1, G10);     \
    f32x4 R01 = MFMA16(w1, bh0, G01);    f32x4 R11 = MFMA16(w1, bh1, G11);     \
    f32x4 Z00 = MFMA16(w2, bh0, G02);    f32x4 Z10 = MFMA16(w2, bh1, G12);     \
    f32x4 Z01 = MFMA16(w3, bh0, G03);    f32x4 Z11 = MFMA16(w3, bh1, G13);     \
    f32x4 H04 = MFMA16(w4, bh0, cH4);    f32x4 H14 = MFMA16(w4, bh1, cH4);     \
    f32x4 H05 = MFMA16(w5, bh0, cH5);    f32x4 H15 = MFMA16(w5, bh1, cH5);     \
    _Pragma("unroll")                                                          \
    for (int r = 0; r < 4; ++r) {                                              \
      float r00 = sig2(R00[r]);                                                \
      float r01 = sig2(R01[r]);                                                \
      float z00 = sig2(Z00[r]);                                                \
      float z01 = sig2(Z01[r]);                                                \
      float n00 = tanh2(__builtin_fmaf(r00, H04[r], G04[r]));                  \
      float n01 = tanh2(__builtin_fmaf(r01, H05[r], G05[r]));                  \
      h0a[r] = n00 + z00 * (h0a[r] - n00);                                     \
      h0b[r] = n01 + z01 * (h0b[r] - n01);                                     \
      float r10 = sig2(R10[r]);                                                \
      float r11 = sig2(R11[r]);                                                \
      float z10 = sig2(Z10[r]);                                                \
      float z11 = sig2(Z11[r]);                                                \
      float n10 = tanh2(__builtin_fmaf(r10, H14[r], G14[r]));                  \
      float n11 = tanh2(__builtin_fmaf(r11, H15[r], G15[r]));                  \
      h1a[r] = n10 + z10 * (h1a[r] - n10);                                     \
      h1b[r] = n11 + z11 * (h1b[r] - n11);                                     \
    }                                                                          \
  } while (0)

  // prologue: x[0] -> slab0, x[1] -> slab1 (8 gl_lds outstanding)
  ISSUE_X(0);
  ISSUE_X(1);

  // steady state: read slab t%3, write slab (t+2)%3, always 8-12 in flight
#pragma unroll 1
  for (int tt = 0; tt < 7; ++tt) {
    STEPW(0, 2, true, "vmcnt(8)");   // t=3tt
    STEPW(1, 0, true, "vmcnt(8)");   // t=3tt+1
    STEPW(2, 1, true, "vmcnt(8)");   // t=3tt+2
  }
  // tail (tt=7): t=21 issues x[23]; t=22/23 drain with exact counts
  STEPW(0, 2, true,  "vmcnt(8)");    // t=21
  STEPW(1, 0, false, "vmcnt(4)");    // t=22
  STEPW(2, 1, false, "vmcnt(0)");    // t=23

  // epilogue: out^T(16x16) = W^T(16x32) @ h^T(32x16) per group.
  // B-frag is the tau-packed state, so Wout rows are read tau-permuted.
  bf16x8 bhf0 = pack8(h0a, h0b);
  bf16x8 bhf1 = pack8(h1a, h1b);
  float w[8];
#pragma unroll
  for (int j = 0; j < 8; ++j) {
    int tk = (j < 4) ? (q * 4 + j) : (16 + q * 4 + (j - 4));   // tau(q*8+j)
    w[j] = Wout[tk * 16 + col];
  }
  u32x4 awp = { pk2(w[0], w[1]), pk2(w[2], w[3]), pk2(w[4], w[5]), pk2(w[6], w[7]) };
  bf16x8 aw = __builtin_bit_cast(bf16x8, awp);
  f32x4 o0 = MFMA16(aw, bhf0, zero);
  f32x4 o1 = MFMA16(aw, bhf1, zero);
  *(f32x4*)&out[p0 * 16 + q * 4] = o0;
  *(f32x4*)&out[p1 * 16 + q * 4] = o1;
}

extern "C" void kernel_launch(void* const* d_in, const int* in_sizes, int n_in,
                              void* d_out, int out_size, void* d_ws, size_t ws_size,
                              hipStream_t stream) {
  const float* spatial = (const float*)d_in[0];
  const float* met     = (const float*)d_in[1];
  const float* ctx     = (const float*)d_in[2];
  const float* W_ih    = (const float*)d_in[3];
  const float* W_hh    = (const float*)d_in[4];
  const float* b_ih    = (const float*)d_in[5];
  const float* b_hh    = (const float*)d_in[6];
  const float* Wout    = (const float*)d_in[7];
  float* out = (float*)d_out;

  // 2048 waves x 32 px; 512 blocks of 256 = 2 blocks/CU, 8 waves/CU
  gru_fused<<<dim3(NPIX / 32 / 4), dim3(256), 0, stream>>>(
      spatial, met, ctx, W_ih, W_hh, b_ih, b_hh, Wout, out);
}

// Round 6
// 234.018 us; speedup vs baseline: 1.0209x; 1.0150x over previous
//
#include <hip/hip_runtime.h>
#include <hip/hip_bf16.h>

// GRU fused kernel for MI355X (gfx950). R10b: DENSE single-region ingest
// (re-run; R10's bench was an infra failure — container died twice — not a
// kernel verdict. Source audited: no barriers in loop, self-satisfying
// counted vmcnt, 65024B LDS <= 64KB, wave-uniform gl_lds dests; identical
// builtin pattern passed in R9.)
// R5-R9 evidence: ~90us invariant across five schedules incl. R9's counted
// vmcnt(8) gl_lds ring (latency provably off critical path). The invariant
// across all five is the scattered request stream: 16B/lane at 64B stride,
// each instruction touching spatial+met+ctx => 2x transactions per byte and
// 3+ TLB translations per instruction. R10 makes each gl_lds a dense 1KB
// burst from ONE array (lane l <- base + l*16B): inst0/1 = spatial px 0-15/
// 16-31 of the wave's 32-px slab, inst2 = met, inst3 = ctx. Slab lands
// px-major in LDS; the q-scatter moves to ds_read_b128 (per-lane offset,
// ~2x bank cost on 4 reads/step — noise). Ring + counted vmcnt(8) +
// tau-packed shuffle-free recurrence + hoisted weights + exp2 gates kept.
// T=24, N=65536, F=H=32, gates r,z,n; one wave = 32 px.

#define TSTEPS 24
#define NPIX 65536
#define PADW 40          // shorts per weight row in LDS (80 B)
#define RING_STEP 16384  // bytes per ring slab: 4 waves * 4 KB

typedef __attribute__((ext_vector_type(8))) short bf16x8;
typedef __attribute__((ext_vector_type(4))) float f32x4;
typedef __attribute__((ext_vector_type(4))) unsigned int u32x4;

#define MFMA16(a, b, c) __builtin_amdgcn_mfma_f32_16x16x32_bf16((a), (b), (c), 0, 0, 0)

#define SCL_RZ (-1.4426950408889634f)   // -log2(e)
#define SCL_N  ( 2.8853900817779268f)   // 2*log2(e)

__device__ __forceinline__ unsigned short f2bf(float f) {
  unsigned u = __builtin_bit_cast(unsigned, f);
  u += 0x7fffu + ((u >> 16) & 1u);   // RNE (one-time staging only)
  return (unsigned short)(u >> 16);
}

__device__ __forceinline__ unsigned pk2(float a, float b) {
  __hip_bfloat162 h = __float22bfloat162_rn(float2{a, b});
  unsigned u;
  __builtin_memcpy(&u, &h, sizeof(u));
  return u;
}

__device__ __forceinline__ bf16x8 pack8(f32x4 a, f32x4 b) {
  u32x4 r = { pk2(a[0], a[1]), pk2(a[2], a[3]), pk2(b[0], b[1]), pk2(b[2], b[3]) };
  return __builtin_bit_cast(bf16x8, r);
}

__device__ __forceinline__ float sig2(float t) {
  return __builtin_amdgcn_rcpf(1.f + __builtin_amdgcn_exp2f(t));
}
__device__ __forceinline__ float tanh2(float t) {
  return 1.f - 2.f * __builtin_amdgcn_rcpf(1.f + __builtin_amdgcn_exp2f(t));
}

// tau: B-fragment k-slot -> state position (C-layout row), per 8-slot quad
__device__ __forceinline__ int tau(int k) {
  int q = k >> 3, j = k & 7;
  return (j < 4) ? (q * 4 + j) : (16 + q * 4 + (j - 4));
}

#define AS1 __attribute__((address_space(1)))
#define AS3 __attribute__((address_space(3)))

__global__ __launch_bounds__(256, 2)
void gru_fused(const float* __restrict__ spatial, const float* __restrict__ met,
               const float* __restrict__ ctx,
               const float* __restrict__ W_ih, const float* __restrict__ W_hh,
               const float* __restrict__ b_ih, const float* __restrict__ b_hh,
               const float* __restrict__ Wout, float* __restrict__ out) {
  // x-ingest ring: 3 slabs x (4 waves x 4 KB). Wave-private regions.
  // slab layout (per wave, 4 KB): [0,2048) spatial px-major (px*64+byte),
  // [2048,3072) met (px*32+byte), [3072,4096) ctx (px*32+byte).
  __shared__ __align__(16) unsigned char ring[3 * RING_STEP];
  // rows 0..95 = W_ih (scaled), rows 96..191 = W_hh (scaled, tau-permuted cols)
  __shared__ __align__(16) unsigned short sW[192 * PADW];
  __shared__ __align__(16) float sCB[64];
  __shared__ __align__(16) float sBIN[32];
  __shared__ __align__(16) float sBHN[32];

  const int tid = threadIdx.x;
  for (int i = tid; i < 96 * 32; i += 256) {
    int r = i >> 5, c = i & 31;
    float s = (r < 64) ? SCL_RZ : SCL_N;
    sW[r * PADW + c] = f2bf(W_ih[i] * s);
    sW[(96 + r) * PADW + c] = f2bf(W_hh[r * 32 + tau(c)] * s);
  }
  if (tid < 64) sCB[tid] = (b_ih[tid] + b_hh[tid]) * SCL_RZ;
  else if (tid < 96) sBIN[tid - 64] = b_ih[tid] * SCL_N;
  else if (tid < 128) sBHN[tid - 96] = b_hh[tid - 32] * SCL_N;
  __syncthreads();

  const int lane = tid & 63;
  const int col = lane & 15;
  const int q = lane >> 4;
  const int wv = tid >> 6;                  // wave in block
  const int wave = blockIdx.x * 4 + wv;
  const long p0 = (long)wave * 32 + col;    // group 0 pixel (global, for out)
  const long p1 = p0 + 16;                  // group 1 pixel

  // biases resident (read once from LDS), pre-scaled
  f32x4 cS[4];
#pragma unroll
  for (int i = 0; i < 4; ++i) cS[i] = *(const f32x4*)&sCB[i * 16 + q * 4];
  const f32x4 cG4 = *(const f32x4*)&sBIN[q * 4];
  const f32x4 cG5 = *(const f32x4*)&sBIN[16 + q * 4];
  const f32x4 cH4 = *(const f32x4*)&sBHN[q * 4];
  const f32x4 cH5 = *(const f32x4*)&sBHN[16 + q * 4];

  // weight fragments hoisted to registers once (loop-invariant)
  const int wb = col * PADW + q * 8;
  const bf16x8 a0 = *(const bf16x8*)&sW[wb];
  const bf16x8 a1 = *(const bf16x8*)&sW[wb + 16 * PADW];
  const bf16x8 a2 = *(const bf16x8*)&sW[wb + 32 * PADW];
  const bf16x8 a3 = *(const bf16x8*)&sW[wb + 48 * PADW];
  const bf16x8 a4 = *(const bf16x8*)&sW[wb + 64 * PADW];
  const bf16x8 a5 = *(const bf16x8*)&sW[wb + 80 * PADW];
  const bf16x8 w0 = *(const bf16x8*)&sW[wb + 96 * PADW];
  const bf16x8 w1 = *(const bf16x8*)&sW[wb + 112 * PADW];
  const bf16x8 w2 = *(const bf16x8*)&sW[wb + 128 * PADW];
  const bf16x8 w3 = *(const bf16x8*)&sW[wb + 144 * PADW];
  const bf16x8 w4 = *(const bf16x8*)&sW[wb + 160 * PADW];
  const bf16x8 w5 = *(const bf16x8*)&sW[wb + 176 * PADW];

  // DENSE wave-slab stream pointers (wave-uniform; lane offset added in gl_lds)
  const long pbase = (long)wave * 32;
  const float* xs = spatial + pbase * 16;   // 32 px * 16 f = 512 f / step
  const float* xm = met + pbase * 8;        // 32 px * 8 f  = 256 f / step
  const float* xc = ctx + pbase * 8;        // 32 px * 8 f  = 256 f / step

  // per-lane LDS read offsets into the slab (computed once)
  int r0off, r1off;
  if (q < 2) {        // spatial: px-major 64 B rows; quarter q*32 (+16)
    r0off = col * 64 + q * 32;
    r1off = 1024 + col * 64 + q * 32;
  } else if (q == 2) { // met: px-major 32 B rows
    r0off = 2048 + col * 32;
    r1off = 2048 + (16 + col) * 32;
  } else {             // ctx
    r0off = 3072 + col * 32;
    r1off = 3072 + (16 + col) * 32;
  }

  // 4 dense 1 KB bursts, each from ONE array, lane l <- base + l*16 B.
  // (All staging vmem drained before the loop, so these are the only vmcnt
  //  events: the counted waits below are exact.)
#define ISSUE_X(SLAB)                                                          \
  do {                                                                         \
    unsigned char* lb = &ring[(SLAB) * RING_STEP + wv * 4096];                 \
    __builtin_amdgcn_global_load_lds((const AS1 unsigned int*)(xs + lane * 4), \
                                     (AS3 unsigned int*)(lb), 16, 0, 0);       \
    __builtin_amdgcn_global_load_lds((const AS1 unsigned int*)(xs + 256 + lane * 4), \
                                     (AS3 unsigned int*)(lb + 1024), 16, 0, 0);\
    __builtin_amdgcn_global_load_lds((const AS1 unsigned int*)(xm + lane * 4), \
                                     (AS3 unsigned int*)(lb + 2048), 16, 0, 0);\
    __builtin_amdgcn_global_load_lds((const AS1 unsigned int*)(xc + lane * 4), \
                                     (AS3 unsigned int*)(lb + 3072), 16, 0, 0);\
    xs += (long)NPIX * 16; xm += (long)NPIX * 8; xc += (long)NPIX * 8;         \
  } while (0)

  f32x4 h0a = {0.f, 0.f, 0.f, 0.f}, h0b = {0.f, 0.f, 0.f, 0.f};   // group 0
  f32x4 h1a = {0.f, 0.f, 0.f, 0.f}, h1b = {0.f, 0.f, 0.f, 0.f};   // group 1
  const f32x4 zero = {0.f, 0.f, 0.f, 0.f};

  // One step: issue loads for t+2 into slab WS, counted-wait for slab RS,
  // consume RS via per-lane ds_read offsets, compute.
#define STEPW(RS, WS, DOLOAD, WAIT)                                            \
  do {                                                                         \
    if (DOLOAD) ISSUE_X(WS);                                                   \
    asm volatile("s_waitcnt " WAIT ::: "memory");                              \
    __builtin_amdgcn_sched_barrier(0);                                         \
    const unsigned char* sb = &ring[(RS) * RING_STEP + wv * 4096];             \
    f32x4 x0a = *(const f32x4*)(sb + r0off);                                   \
    f32x4 x0b = *(const f32x4*)(sb + r0off + 16);                              \
    f32x4 x1a = *(const f32x4*)(sb + r1off);                                   \
    f32x4 x1b = *(const f32x4*)(sb + r1off + 16);                              \
    bf16x8 bx0 = pack8(x0a, x0b);                                              \
    bf16x8 bx1 = pack8(x1a, x1b);                                              \
    bf16x8 bh0 = pack8(h0a, h0b);                                              \
    bf16x8 bh1 = pack8(h1a, h1b);                                              \
    f32x4 G00 = MFMA16(a0, bx0, cS[0]);  f32x4 G10 = MFMA16(a0, bx1, cS[0]);   \
    f32x4 G01 = MFMA16(a1, bx0, cS[1]);  f32x4 G11 = MFMA16(a1, bx1, cS[1]);   \
    f32x4 G02 = MFMA16(a2, bx0, cS[2]);  f32x4 G12 = MFMA16(a2, bx1, cS[2]);   \
    f32x4 G03 = MFMA16(a3, bx0, cS[3]);  f32x4 G13 = MFMA16(a3, bx1, cS[3]);   \
    f32x4 G04 = MFMA16(a4, bx0, cG4);    f32x4 G14 = MFMA16(a4, bx1, cG4);     \
    f32x4 G05 = MFMA16(a5, bx0, cG5);    f32x4 G15 = MFMA16(a5, bx1, cG5);     \
    f32x4 R00 = MFMA16(w0, bh0, G00);    f32x4 R10 = MFMA16(w0, bh1, G10);     \
    f32x4 R01 = MFMA16(w1, bh0, G01);    f32x4 R11 = MFMA16(w1, bh1, G11);     \
    f32x4 Z00 = MFMA16(w2, bh0, G02);    f32x4 Z10 = MFMA16(w2, bh1, G12);     \
    f32x4 Z01 = MFMA16(w3, bh0, G03);    f32x4 Z11 = MFMA16(w3, bh1, G13);     \
    f32x4 H04 = MFMA16(w4, bh0, cH4);    f32x4 H14 = MFMA16(w4, bh1, cH4);     \
    f32x4 H05 = MFMA16(w5, bh0, cH5);    f32x4 H15 = MFMA16(w5, bh1, cH5);     \
    _Pragma("unroll")                                                          \
    for (int r = 0; r < 4; ++r) {                                              \
      float r00 = sig2(R00[r]);                                                \
      float r01 = sig2(R01[r]);                                                \
      float z00 = sig2(Z00[r]);                                                \
      float z01 = sig2(Z01[r]);                                                \
      float n00 = tanh2(__builtin_fmaf(r00, H04[r], G04[r]));                  \
      float n01 = tanh2(__builtin_fmaf(r01, H05[r], G05[r]));                  \
      h0a[r] = n00 + z00 * (h0a[r] - n00);                                     \
      h0b[r] = n01 + z01 * (h0b[r] - n01);                                     \
      float r10 = sig2(R10[r]);                                                \
      float r11 = sig2(R11[r]);                                                \
      float z10 = sig2(Z10[r]);                                                \
      float z11 = sig2(Z11[r]);                                                \
      float n10 = tanh2(__builtin_fmaf(r10, H14[r], G14[r]));                  \
      float n11 = tanh2(__builtin_fmaf(r11, H15[r], G15[r]));                  \
      h1a[r] = n10 + z10 * (h1a[r] - n10);                                     \
      h1b[r] = n11 + z11 * (h1b[r] - n11);                                     \
    }                                                                          \
  } while (0)

  // prologue: x[0] -> slab0, x[1] -> slab1 (8 gl_lds outstanding)
  ISSUE_X(0);
  ISSUE_X(1);

  // steady state: read slab t%3, write slab (t+2)%3, always 8-12 in flight
#pragma unroll 1
  for (int tt = 0; tt < 7; ++tt) {
    STEPW(0, 2, true, "vmcnt(8)");   // t=3tt
    STEPW(1, 0, true, "vmcnt(8)");   // t=3tt+1
    STEPW(2, 1, true, "vmcnt(8)");   // t=3tt+2
  }
  // tail (tt=7): t=21 issues x[23]; t=22/23 drain with exact counts
  STEPW(0, 2, true,  "vmcnt(8)");    // t=21
  STEPW(1, 0, false, "vmcnt(4)");    // t=22
  STEPW(2, 1, false, "vmcnt(0)");    // t=23

  // epilogue: out^T(16x16) = W^T(16x32) @ h^T(32x16) per group.
  // B-frag is the tau-packed state, so Wout rows are read tau-permuted.
  bf16x8 bhf0 = pack8(h0a, h0b);
  bf16x8 bhf1 = pack8(h1a, h1b);
  float w[8];
#pragma unroll
  for (int j = 0; j < 8; ++j) {
    int tk = (j < 4) ? (q * 4 + j) : (16 + q * 4 + (j - 4));   // tau(q*8+j)
    w[j] = Wout[tk * 16 + col];
  }
  u32x4 awp = { pk2(w[0], w[1]), pk2(w[2], w[3]), pk2(w[4], w[5]), pk2(w[6], w[7]) };
  bf16x8 aw = __builtin_bit_cast(bf16x8, awp);
  f32x4 o0 = MFMA16(aw, bhf0, zero);
  f32x4 o1 = MFMA16(aw, bhf1, zero);
  *(f32x4*)&out[p0 * 16 + q * 4] = o0;
  *(f32x4*)&out[p1 * 16 + q * 4] = o1;
}

extern "C" void kernel_launch(void* const* d_in, const int* in_sizes, int n_in,
                              void* d_out, int out_size, void* d_ws, size_t ws_size,
                              hipStream_t stream) {
  const float* spatial = (const float*)d_in[0];
  const float* met     = (const float*)d_in[1];
  const float* ctx     = (const float*)d_in[2];
  const float* W_ih    = (const float*)d_in[3];
  const float* W_hh    = (const float*)d_in[4];
  const float* b_ih    = (const float*)d_in[5];
  const float* b_hh    = (const float*)d_in[6];
  const float* Wout    = (const float*)d_in[7];
  float* out = (float*)d_out;

  // 2048 waves x 32 px; 512 blocks of 256 = 2 blocks/CU, 8 waves/CU
  gru_fused<<<dim3(NPIX / 32 / 4), dim3(256), 0, stream>>>(
      spatial, met, ctx, W_ih, W_hh, b_ih, b_hh, Wout, out);
}